// Round 12
// baseline (264.861 us; speedup 1.0000x reference)
//
#include <hip/hip_runtime.h>
#include <hip/hip_bf16.h>

#define NEG_SLOPE 0.2f
#define BN_EPS 1e-5f

#define NBLK 256
#define COARSE_SHIFT 9
#define COARSE_NPB 512

__device__ __forceinline__ float wred_sum(float v) {
    #pragma unroll
    for (int m = 32; m > 0; m >>= 1) v += __shfl_xor(v, m);
    return v;
}
__device__ __forceinline__ float wred_max(float v) {
    #pragma unroll
    for (int m = 32; m > 0; m >>= 1) v = fmaxf(v, __shfl_xor(v, m));
    return v;
}
__device__ __forceinline__ int wred_isum(int v) {
    #pragma unroll
    for (int m = 32; m > 0; m >>= 1) v += __shfl_xor(v, m);
    return v;
}
__device__ __forceinline__ float xor16_sum(float v) {
    #pragma unroll
    for (int m = 1; m < 16; m <<= 1) v += __shfl_xor(v, m);
    return v;
}

__device__ __forceinline__ unsigned pack_bf16(float a, float b) {
    __hip_bfloat162 t;
    t.x = __float2bfloat16(a);
    t.y = __float2bfloat16(b);
    return *(unsigned*)&t;
}
__device__ __forceinline__ float2 unpack_bf16(unsigned u) {
    __hip_bfloat162 t = *(__hip_bfloat162*)&u;
    return {__bfloat162float(t.x), __bfloat162float(t.y)};
}

__device__ __forceinline__ unsigned enc_ord(float f) {
    unsigned u = __float_as_uint(f);
    return (u & 0x80000000u) ? ~u : (u | 0x80000000u);
}
__device__ __forceinline__ float dec_ord(unsigned e) {
    unsigned u = (e & 0x80000000u) ? (e ^ 0x80000000u) : ~e;
    return __uint_as_float(u);
}

// ---- CSR build: per-block coarse histogram (LDS only) ----
__global__ __launch_bounds__(256) void part_hist(const int* __restrict__ ei, int E, int Et,
                                                 int chunk, int* __restrict__ hist, int nCoarse) {
    __shared__ int h[128];
    int b = blockIdx.x, t = threadIdx.x;
    if (t < 128) h[t] = 0;
    __syncthreads();
    int beg = b * chunk, end = min(beg + chunk, Et);
    for (int idx = beg + t; idx < end; idx += 256) {
        int d = (idx < E) ? ei[E + idx] : (idx - E);
        atomicAdd(&h[d >> COARSE_SHIFT], 1);
    }
    __syncthreads();
    if (t < nCoarse) hist[t * NBLK + b] = h[t];
}

// ---- fused: bucket totals + bucket scan + per-(bucket,block) scan, all in one block ----
__global__ __launch_bounds__(1024) void csr_mid(int* __restrict__ hist,
                                                int* __restrict__ cbase, int nCoarse) {
    __shared__ int ctot_s[128];
    __shared__ int scn[128];
    __shared__ int cb_s[129];
    int t = threadIdx.x;
    int wv = t >> 6, ln = t & 63;      // 16 waves
    if (t < 128) ctot_s[t] = 0;
    __syncthreads();
    // pass 1: per-bucket totals (one wave per bucket, strided)
    for (int c = wv; c < nCoarse; c += 16) {
        int idx = c * NBLK + 4 * ln;
        int4 v = *(int4*)&hist[idx];
        int s = wred_isum(v.x + v.y + v.z + v.w);
        if (ln == 0) ctot_s[c] = s;
    }
    __syncthreads();
    // scan of <=128 bucket totals (Hillis-Steele; barriers unconditional)
    int v0 = 0;
    if (t < 128) { v0 = ctot_s[t]; scn[t] = v0; }
    __syncthreads();
    for (int off = 1; off < 128; off <<= 1) {
        int u = (t >= off && t < 128) ? scn[t - off] : 0;
        __syncthreads();
        if (t < 128) scn[t] += u;
        __syncthreads();
    }
    if (t < 128) cb_s[t] = scn[t] - v0;
    if (t == 127) cb_s[128] = scn[127];
    __syncthreads();
    if (t <= nCoarse) cbase[t] = cb_s[t];
    // pass 2: per-bucket exclusive scan of the NBLK block counts
    for (int c = wv; c < nCoarse; c += 16) {
        int base = cb_s[c];
        int idx = c * NBLK + 4 * ln;
        int4 v = *(int4*)&hist[idx];
        int sl = v.x + v.y + v.z + v.w;
        int inc = sl;
        #pragma unroll
        for (int off = 1; off < 64; off <<= 1) {
            int u = __shfl_up(inc, off);
            if (ln >= off) inc += u;
        }
        int exc = inc - sl + base;
        int4 o;
        o.x = exc;
        o.y = exc + v.x;
        o.z = exc + v.x + v.y;
        o.w = exc + v.x + v.y + v.z;
        *(int4*)&hist[idx] = o;
    }
}

__global__ __launch_bounds__(256) void part_scatter(const int* __restrict__ ei, int E, int Et,
                                                    int chunk, const int* __restrict__ hist,
                                                    unsigned* __restrict__ staged, int nCoarse) {
    __shared__ int cur[128];
    int b = blockIdx.x, t = threadIdx.x;
    if (t < nCoarse) cur[t] = hist[t * NBLK + b];
    __syncthreads();
    int beg = b * chunk, end = min(beg + chunk, Et);
    for (int idx = beg + t; idx < end; idx += 256) {
        int s, d;
        if (idx < E) { s = ei[idx]; d = ei[E + idx]; }
        else         { s = idx - E; d = idx - E; }
        int c = d >> COARSE_SHIFT;
        int pos = atomicAdd(&cur[c], 1);
        staged[pos] = ((unsigned)s << COARSE_SHIFT) | (unsigned)(d & (COARSE_NPB - 1));
    }
}

__global__ __launch_bounds__(512) void fine_place(const unsigned* __restrict__ staged,
                                                  const int* __restrict__ cbase,
                                                  int* __restrict__ offs,
                                                  int* __restrict__ csr, int Nn, int nCoarse) {
    __shared__ int hcnt[COARSE_NPB];
    __shared__ int scn[COARSE_NPB];
    int b = blockIdx.x, t = threadIdx.x;
    int node0 = b << COARSE_SHIFT;
    int nloc = min(COARSE_NPB, Nn - node0);
    hcnt[t] = 0;
    __syncthreads();
    int ebeg = cbase[b], eend = cbase[b + 1];
    for (int p = ebeg + t; p < eend; p += 512) {
        atomicAdd(&hcnt[staged[p] & (COARSE_NPB - 1)], 1);
    }
    __syncthreads();
    int val = hcnt[t];
    scn[t] = val;
    __syncthreads();
    for (int off = 1; off < COARSE_NPB; off <<= 1) {
        int u = (t >= off) ? scn[t - off] : 0;
        __syncthreads();
        scn[t] += u;
        __syncthreads();
    }
    int exc = ebeg + scn[t] - val;
    if (t < nloc) offs[node0 + t] = exc;
    if (b == nCoarse - 1 && t == 0) offs[Nn] = eend;
    hcnt[t] = exc;
    __syncthreads();
    for (int p = ebeg + t; p < eend; p += 512) {
        unsigned v = staged[p];
        int pos = atomicAdd(&hcnt[v & (COARSE_NPB - 1)], 1);
        csr[pos] = (int)(v >> COARSE_SHIFT);
    }
}

// ---------------- Layer 1 GEMM (128x128 tile, 8x8 micro, transposed-A LDS) + fused al1 ----------------
__global__ __launch_bounds__(256) void gemm1_tiled(const float* __restrict__ x,
                                                   const float* __restrict__ W,
                                                   const float* __restrict__ a1s,
                                                   const float* __restrict__ a1d,
                                                   unsigned* __restrict__ h1b,
                                                   float* __restrict__ als,
                                                   float* __restrict__ ald, int Nn) {
    __shared__ float Ast[32][132];
    __shared__ float Bs[32][132];
    int t  = threadIdx.x;
    int tx = t & 15;
    int ty = t >> 4;
    int br = blockIdx.x * 128;

    float acc[8][8];
    #pragma unroll
    for (int i = 0; i < 8; ++i)
        #pragma unroll
        for (int j = 0; j < 8; ++j) acc[i][j] = 0.f;

    int k4   = t & 7;
    int rowA = t >> 3;

    for (int k0 = 0; k0 < 128; k0 += 32) {
        #pragma unroll
        for (int i = 0; i < 4; ++i) {
            int r  = rowA + 32 * i;
            int gr = min(br + r, Nn - 1);
            float4 v = *(const float4*)(x + (size_t)gr * 128 + k0 + 4 * k4);
            Ast[4 * k4 + 0][r] = v.x; Ast[4 * k4 + 1][r] = v.y;
            Ast[4 * k4 + 2][r] = v.z; Ast[4 * k4 + 3][r] = v.w;
        }
        #pragma unroll
        for (int i = 0; i < 4; ++i) {
            int f  = t + 256 * i;
            int kk = f >> 5, c4 = f & 31;
            *(float4*)&Bs[kk][4 * c4] = *(const float4*)(W + (size_t)(k0 + kk) * 128 + 4 * c4);
        }
        __syncthreads();
        #pragma unroll 8
        for (int kk = 0; kk < 32; ++kk) {
            float4 a0 = *(const float4*)&Ast[kk][8 * ty];
            float4 a1 = *(const float4*)&Ast[kk][8 * ty + 4];
            float4 b0 = *(const float4*)&Bs[kk][8 * tx];
            float4 b1 = *(const float4*)&Bs[kk][8 * tx + 4];
            float av[8] = {a0.x, a0.y, a0.z, a0.w, a1.x, a1.y, a1.z, a1.w};
            float bv[8] = {b0.x, b0.y, b0.z, b0.w, b1.x, b1.y, b1.z, b1.w};
            #pragma unroll
            for (int i = 0; i < 8; ++i)
                #pragma unroll
                for (int j = 0; j < 8; ++j) acc[i][j] += av[i] * bv[j];
        }
        __syncthreads();
    }

    float a_s[8], a_d[8];
    #pragma unroll
    for (int j = 0; j < 8; ++j) { a_s[j] = a1s[8 * tx + j]; a_d[j] = a1d[8 * tx + j]; }
    bool h0 = (tx < 8);

    #pragma unroll
    for (int i = 0; i < 8; ++i) {
        int r = br + 8 * ty + i;
        if (r < Nn) {
            uint4 pk;
            pk.x = pack_bf16(acc[i][0], acc[i][1]);
            pk.y = pack_bf16(acc[i][2], acc[i][3]);
            pk.z = pack_bf16(acc[i][4], acc[i][5]);
            pk.w = pack_bf16(acc[i][6], acc[i][7]);
            *(uint4*)(h1b + (size_t)r * 64 + 4 * tx) = pk;
        }
        float ps = 0.f, pd = 0.f;
        #pragma unroll
        for (int j = 0; j < 8; ++j) { ps += acc[i][j] * a_s[j]; pd += acc[i][j] * a_d[j]; }
        float s0 = xor16_sum(h0 ? ps : 0.f);
        float s1 = xor16_sum(h0 ? 0.f : ps);
        float d0 = xor16_sum(h0 ? pd : 0.f);
        float d1 = xor16_sum(h0 ? 0.f : pd);
        if (tx == 0 && r < Nn) {
            als[r * 2] = s0; als[r * 2 + 1] = s1;
            ald[r * 2] = d0; ald[r * 2 + 1] = d1;
        }
    }
}

// ---- global max of als per head + (block 0) BN scale/shift precompute ----
template <int H>
__global__ __launch_bounds__(256) void almax_kernel(const float* __restrict__ als,
                                                    unsigned* __restrict__ gmax, int off, int Nn,
                                                    const float* __restrict__ b1,
                                                    const float* __restrict__ g1,
                                                    const float* __restrict__ be1,
                                                    const float* __restrict__ mn1,
                                                    const float* __restrict__ vr1,
                                                    float* __restrict__ bnscale,
                                                    float* __restrict__ bnshift) {
    __shared__ float red[4][H];
    int t = threadIdx.x;
    if (bnscale && blockIdx.x == 0 && t < 128) {
        float sc = rsqrtf(vr1[t] + BN_EPS) * g1[t];
        bnscale[t] = sc;
        bnshift[t] = be1[t] + (b1[t] - mn1[t]) * sc;
    }
    float m[H];
    #pragma unroll
    for (int h = 0; h < H; ++h) m[h] = -1e30f;
    for (int n = blockIdx.x * 256 + t; n < Nn; n += gridDim.x * 256) {
        #pragma unroll
        for (int h = 0; h < H; ++h) m[h] = fmaxf(m[h], als[n * H + h]);
    }
    #pragma unroll
    for (int h = 0; h < H; ++h) m[h] = wred_max(m[h]);
    int wid = t >> 6;
    if ((t & 63) == 0) {
        #pragma unroll
        for (int h = 0; h < H; ++h) red[wid][h] = m[h];
    }
    __syncthreads();
    if (t == 0) {
        #pragma unroll
        for (int h = 0; h < H; ++h) {
            float mm = fmaxf(fmaxf(red[0][h], red[1][h]), fmaxf(red[2][h], red[3][h]));
            atomicMax(&gmax[off + h], enc_ord(mm));
        }
    }
}

// ---------------- two-phase softagg1 (LDS handoff, 2x unrolled gather, bf16 out) ----------------
__global__ __launch_bounds__(256) void softagg1_kernel(const int* __restrict__ offs, const int* __restrict__ csr,
                            const unsigned* __restrict__ h1b,
                            const float* __restrict__ als, const float* __restrict__ ald,
                            const unsigned* __restrict__ gmax,
                            const float* __restrict__ bnscale, const float* __restrict__ bnshift,
                            unsigned* __restrict__ hbnb, int Nn) {
    __shared__ int   sh_s[4][64];
    __shared__ float sh_e0[4][64];
    __shared__ float sh_e1[4][64];
    int wid = threadIdx.x >> 6, lane = threadIdx.x & 63;
    int n = blockIdx.x * 4 + wid;
    if (n >= Nn) return;
    int b = offs[n], e = offs[n + 1];
    float2 aldn = *(const float2*)(ald + n * 2);
    float bd0 = dec_ord(gmax[0]) + aldn.x; bd0 = (bd0 > 0.f) ? bd0 : NEG_SLOPE * bd0;
    float bd1 = dec_ord(gmax[1]) + aldn.y; bd1 = (bd1 > 0.f) ? bd1 : NEG_SLOPE * bd1;

    int eslot = lane >> 3;
    int l8    = lane & 7;
    float acc[16];
    #pragma unroll
    for (int j = 0; j < 16; ++j) acc[j] = 0.f;
    float den0 = 0.f, den1 = 0.f;

    for (int base = b; base < e; base += 64) {
        int cnt = min(64, e - base);
        int   s1 = 0;
        float e0r = 0.f, e1r = 0.f;
        if (lane < cnt) {
            s1 = csr[base + lane];
            float2 as = *(const float2*)(als + (size_t)s1 * 2);
            float l0 = as.x + aldn.x; l0 = (l0 > 0.f) ? l0 : NEG_SLOPE * l0;
            float l1 = as.y + aldn.y; l1 = (l1 > 0.f) ? l1 : NEG_SLOPE * l1;
            e0r = __expf(l0 - bd0);
            e1r = __expf(l1 - bd1);
            den0 += e0r; den1 += e1r;
        }
        sh_s[wid][lane]  = s1;
        sh_e0[wid][lane] = e0r;
        sh_e1[wid][lane] = e1r;
        // phase 2, 2x unrolled: two edges' loads issued before their FMA chains
        int i = eslot;
        for (; i + 8 < cnt; i += 16) {
            int   sA  = sh_s[wid][i];
            int   sB  = sh_s[wid][i + 8];
            float e0A = sh_e0[wid][i],  e1A = sh_e1[wid][i];
            float e0B = sh_e0[wid][i + 8], e1B = sh_e1[wid][i + 8];
            const uint4* pA = (const uint4*)(h1b + (size_t)sA * 64 + 4 * l8);
            const uint4* pB = (const uint4*)(h1b + (size_t)sB * 64 + 4 * l8);
            uint4 vaA = pA[0];
            uint4 vbA = pA[8];     // +32 uints = 8 uint4
            uint4 vaB = pB[0];
            uint4 vbB = pB[8];
            float2 f;
            f = unpack_bf16(vaA.x); acc[0]  += f.x * e0A; acc[1]  += f.y * e0A;
            f = unpack_bf16(vaA.y); acc[2]  += f.x * e0A; acc[3]  += f.y * e0A;
            f = unpack_bf16(vaA.z); acc[4]  += f.x * e0A; acc[5]  += f.y * e0A;
            f = unpack_bf16(vaA.w); acc[6]  += f.x * e0A; acc[7]  += f.y * e0A;
            f = unpack_bf16(vbA.x); acc[8]  += f.x * e1A; acc[9]  += f.y * e1A;
            f = unpack_bf16(vbA.y); acc[10] += f.x * e1A; acc[11] += f.y * e1A;
            f = unpack_bf16(vbA.z); acc[12] += f.x * e1A; acc[13] += f.y * e1A;
            f = unpack_bf16(vbA.w); acc[14] += f.x * e1A; acc[15] += f.y * e1A;
            f = unpack_bf16(vaB.x); acc[0]  += f.x * e0B; acc[1]  += f.y * e0B;
            f = unpack_bf16(vaB.y); acc[2]  += f.x * e0B; acc[3]  += f.y * e0B;
            f = unpack_bf16(vaB.z); acc[4]  += f.x * e0B; acc[5]  += f.y * e0B;
            f = unpack_bf16(vaB.w); acc[6]  += f.x * e0B; acc[7]  += f.y * e0B;
            f = unpack_bf16(vbB.x); acc[8]  += f.x * e1B; acc[9]  += f.y * e1B;
            f = unpack_bf16(vbB.y); acc[10] += f.x * e1B; acc[11] += f.y * e1B;
            f = unpack_bf16(vbB.z); acc[12] += f.x * e1B; acc[13] += f.y * e1B;
            f = unpack_bf16(vbB.w); acc[14] += f.x * e1B; acc[15] += f.y * e1B;
        }
        if (i < cnt) {
            int   s  = sh_s[wid][i];
            float e0 = sh_e0[wid][i], e1 = sh_e1[wid][i];
            const uint4* pR = (const uint4*)(h1b + (size_t)s * 64 + 4 * l8);
            uint4 va = pR[0];
            uint4 vb = pR[8];
            float2 f;
            f = unpack_bf16(va.x); acc[0]  += f.x * e0; acc[1]  += f.y * e0;
            f = unpack_bf16(va.y); acc[2]  += f.x * e0; acc[3]  += f.y * e0;
            f = unpack_bf16(va.z); acc[4]  += f.x * e0; acc[5]  += f.y * e0;
            f = unpack_bf16(va.w); acc[6]  += f.x * e0; acc[7]  += f.y * e0;
            f = unpack_bf16(vb.x); acc[8]  += f.x * e1; acc[9]  += f.y * e1;
            f = unpack_bf16(vb.y); acc[10] += f.x * e1; acc[11] += f.y * e1;
            f = unpack_bf16(vb.z); acc[12] += f.x * e1; acc[13] += f.y * e1;
            f = unpack_bf16(vb.w); acc[14] += f.x * e1; acc[15] += f.y * e1;
        }
    }
    #pragma unroll
    for (int j = 0; j < 16; ++j) {
        acc[j] += __shfl_xor(acc[j], 8);
        acc[j] += __shfl_xor(acc[j], 16);
        acc[j] += __shfl_xor(acc[j], 32);
    }
    den0 = wred_sum(den0);
    den1 = wred_sum(den1);
    if (eslot == 0) {
        float inv0 = 1.f / (den0 + 1e-16f);
        float inv1 = 1.f / (den1 + 1e-16f);
        int c0 = 8 * l8, c1 = 64 + 8 * l8;
        float4 sa = *(const float4*)(bnscale + c0), sb = *(const float4*)(bnscale + c0 + 4);
        float4 ha = *(const float4*)(bnshift + c0), hb = *(const float4*)(bnshift + c0 + 4);
        float o0 = fmaxf(acc[0] * inv0 * sa.x + ha.x, 0.f);
        float o1 = fmaxf(acc[1] * inv0 * sa.y + ha.y, 0.f);
        float o2 = fmaxf(acc[2] * inv0 * sa.z + ha.z, 0.f);
        float o3 = fmaxf(acc[3] * inv0 * sa.w + ha.w, 0.f);
        float o4 = fmaxf(acc[4] * inv0 * sb.x + hb.x, 0.f);
        float o5 = fmaxf(acc[5] * inv0 * sb.y + hb.y, 0.f);
        float o6 = fmaxf(acc[6] * inv0 * sb.z + hb.z, 0.f);
        float o7 = fmaxf(acc[7] * inv0 * sb.w + hb.w, 0.f);
        uint4 pk0 = {pack_bf16(o0, o1), pack_bf16(o2, o3), pack_bf16(o4, o5), pack_bf16(o6, o7)};
        *(uint4*)(hbnb + (size_t)n * 64 + 4 * l8) = pk0;
        float4 sc = *(const float4*)(bnscale + c1), sd = *(const float4*)(bnscale + c1 + 4);
        float4 hc = *(const float4*)(bnshift + c1), hd = *(const float4*)(bnshift + c1 + 4);
        float p0 = fmaxf(acc[8]  * inv1 * sc.x + hc.x, 0.f);
        float p1 = fmaxf(acc[9]  * inv1 * sc.y + hc.y, 0.f);
        float p2 = fmaxf(acc[10] * inv1 * sc.z + hc.z, 0.f);
        float p3 = fmaxf(acc[11] * inv1 * sc.w + hc.w, 0.f);
        float p4 = fmaxf(acc[12] * inv1 * sd.x + hd.x, 0.f);
        float p5 = fmaxf(acc[13] * inv1 * sd.y + hd.y, 0.f);
        float p6 = fmaxf(acc[14] * inv1 * sd.z + hd.z, 0.f);
        float p7 = fmaxf(acc[15] * inv1 * sd.w + hd.w, 0.f);
        uint4 pk1 = {pack_bf16(p0, p1), pack_bf16(p2, p3), pack_bf16(p4, p5), pack_bf16(p6, p7)};
        *(uint4*)(hbnb + (size_t)n * 64 + 32 + 4 * l8) = pk1;
    }
}

// ---------------- Layer 2 GEMM (A from bf16 hbnb) + fused al2 ----------------
__global__ __launch_bounds__(256) void gemm2_tiled(const unsigned* __restrict__ hbnb,
                                                   const float* __restrict__ W2,
                                                   const float* __restrict__ a2s,
                                                   const float* __restrict__ a2d,
                                                   unsigned* __restrict__ h2b,
                                                   float* __restrict__ als, float* __restrict__ ald,
                                                   int Nn) {
    __shared__ float Ast[32][132];
    __shared__ float Bs[32][68];
    int t  = threadIdx.x;
    int tx = t & 15;
    int ty = t >> 4;
    int br = blockIdx.x * 128;

    float as4[4], ad4[4];
    #pragma unroll
    for (int j = 0; j < 4; ++j) {
        int c = 4 * tx + j;
        as4[j] = (c < 40) ? a2s[c] : 0.f;
        ad4[j] = (c < 40) ? a2d[c] : 0.f;
    }

    float acc[8][4];
    #pragma unroll
    for (int i = 0; i < 8; ++i)
        #pragma unroll
        for (int j = 0; j < 4; ++j) acc[i][j] = 0.f;

    int k4   = t & 7;
    int rowA = t >> 3;

    for (int k0 = 0; k0 < 128; k0 += 32) {
        #pragma unroll
        for (int i = 0; i < 4; ++i) {
            int r  = rowA + 32 * i;
            int gr = min(br + r, Nn - 1);
            uint2 v2 = *(const uint2*)(hbnb + (size_t)gr * 64 + (k0 >> 1) + 2 * k4);
            float2 f0 = unpack_bf16(v2.x), f1 = unpack_bf16(v2.y);
            Ast[4 * k4 + 0][r] = f0.x; Ast[4 * k4 + 1][r] = f0.y;
            Ast[4 * k4 + 2][r] = f1.x; Ast[4 * k4 + 3][r] = f1.y;
        }
        #pragma unroll
        for (int i = 0; i < 2; ++i) {
            int f  = t + 256 * i;
            int kk = f >> 4, c4 = f & 15;
            float4 v = {0.f, 0.f, 0.f, 0.f};
            if (c4 < 10) v = *(const float4*)(W2 + (size_t)(k0 + kk) * 40 + 4 * c4);
            *(float4*)&Bs[kk][4 * c4] = v;
        }
        __syncthreads();
        #pragma unroll 8
        for (int kk = 0; kk < 32; ++kk) {
            float4 a0 = *(const float4*)&Ast[kk][8 * ty];
            float4 a1 = *(const float4*)&Ast[kk][8 * ty + 4];
            float4 b0 = *(const float4*)&Bs[kk][4 * tx];
            float av[8] = {a0.x, a0.y, a0.z, a0.w, a1.x, a1.y, a1.z, a1.w};
            #pragma unroll
            for (int i = 0; i < 8; ++i) {
                acc[i][0] += av[i] * b0.x; acc[i][1] += av[i] * b0.y;
                acc[i][2] += av[i] * b0.z; acc[i][3] += av[i] * b0.w;
            }
        }
        __syncthreads();
    }

    #pragma unroll
    for (int i = 0; i < 8; ++i) {
        int r = br + 8 * ty + i;
        if (r < Nn) {
            uint2 pk = {pack_bf16(acc[i][0], acc[i][1]), pack_bf16(acc[i][2], acc[i][3])};
            *(uint2*)(h2b + (size_t)r * 32 + 2 * tx) = pk;
        }
        float ps = acc[i][0] * as4[0] + acc[i][1] * as4[1] + acc[i][2] * as4[2] + acc[i][3] * as4[3];
        float pd = acc[i][0] * ad4[0] + acc[i][1] * ad4[1] + acc[i][2] * ad4[2] + acc[i][3] * ad4[3];
        float sS = xor16_sum(ps);
        float sD = xor16_sum(pd);
        if (tx == 0 && r < Nn) { als[r] = sS; ald[r] = sD; }
    }
}

// ---------------- two-phase softagg2 (LDS handoff, 2x unrolled; + bias + log_softmax) ----------------
__global__ __launch_bounds__(256) void softagg2_kernel(const int* __restrict__ offs, const int* __restrict__ csr,
                            const unsigned* __restrict__ h2b,
                            const float* __restrict__ als, const float* __restrict__ ald,
                            const unsigned* __restrict__ gmax,
                            const float* __restrict__ b2,
                            float* __restrict__ out, int Nn) {
    __shared__ int   sh_s[4][64];
    __shared__ float sh_ev[4][64];
    int wid = threadIdx.x >> 6, lane = threadIdx.x & 63;
    int n = blockIdx.x * 4 + wid;
    if (n >= Nn) return;
    int b = offs[n], e = offs[n + 1];
    float aldn = ald[n];
    float bound = dec_ord(gmax[2]) + aldn;
    bound = (bound > 0.f) ? bound : NEG_SLOPE * bound;

    int eslot = lane >> 3;
    int l8    = lane & 7;
    float acc[8];
    #pragma unroll
    for (int j = 0; j < 8; ++j) acc[j] = 0.f;
    float den = 0.f;

    for (int base = b; base < e; base += 64) {
        int cnt = min(64, e - base);
        int   s1 = 0;
        float evr = 0.f;
        if (lane < cnt) {
            s1 = csr[base + lane];
            float l = als[s1] + aldn;
            l = (l > 0.f) ? l : NEG_SLOPE * l;
            evr = __expf(l - bound);
            den += evr;
        }
        sh_s[wid][lane]  = s1;
        sh_ev[wid][lane] = evr;
        int i = eslot;
        for (; i + 8 < cnt; i += 16) {
            int   sA  = sh_s[wid][i];
            int   sB  = sh_s[wid][i + 8];
            float evA = sh_ev[wid][i];
            float evB = sh_ev[wid][i + 8];
            uint4 vA = *(const uint4*)(h2b + (size_t)sA * 32 + 4 * l8);
            uint4 vB = *(const uint4*)(h2b + (size_t)sB * 32 + 4 * l8);
            float2 f;
            f = unpack_bf16(vA.x); acc[0] += f.x * evA; acc[1] += f.y * evA;
            f = unpack_bf16(vA.y); acc[2] += f.x * evA; acc[3] += f.y * evA;
            f = unpack_bf16(vA.z); acc[4] += f.x * evA; acc[5] += f.y * evA;
            f = unpack_bf16(vA.w); acc[6] += f.x * evA; acc[7] += f.y * evA;
            f = unpack_bf16(vB.x); acc[0] += f.x * evB; acc[1] += f.y * evB;
            f = unpack_bf16(vB.y); acc[2] += f.x * evB; acc[3] += f.y * evB;
            f = unpack_bf16(vB.z); acc[4] += f.x * evB; acc[5] += f.y * evB;
            f = unpack_bf16(vB.w); acc[6] += f.x * evB; acc[7] += f.y * evB;
        }
        if (i < cnt) {
            int   s  = sh_s[wid][i];
            float ev = sh_ev[wid][i];
            uint4 v = *(const uint4*)(h2b + (size_t)s * 32 + 4 * l8);
            float2 f;
            f = unpack_bf16(v.x); acc[0] += f.x * ev; acc[1] += f.y * ev;
            f = unpack_bf16(v.y); acc[2] += f.x * ev; acc[3] += f.y * ev;
            f = unpack_bf16(v.z); acc[4] += f.x * ev; acc[5] += f.y * ev;
            f = unpack_bf16(v.w); acc[6] += f.x * ev; acc[7] += f.y * ev;
        }
    }
    #pragma unroll
    for (int j = 0; j < 8; ++j) {
        acc[j] += __shfl_xor(acc[j], 8);
        acc[j] += __shfl_xor(acc[j], 16);
        acc[j] += __shfl_xor(acc[j], 32);
    }
    den = wred_sum(den);
    float inv = 1.f / (den + 1e-16f);
    bool valid = (eslot == 0) && (l8 < 5);
    float vv[8];
    float lmax = -1e30f;
    if (valid) {
        int c = 8 * l8;
        #pragma unroll
        for (int j = 0; j < 8; ++j) {
            vv[j] = acc[j] * inv + b2[c + j];
            lmax = fmaxf(lmax, vv[j]);
        }
    }
    float m = wred_max(lmax);
    float es = 0.f;
    if (valid) {
        #pragma unroll
        for (int j = 0; j < 8; ++j) es += __expf(vv[j] - m);
    }
    float ssum = wred_sum(es);
    float lse = m + logf(ssum);
    if (valid) {
        float4 oa = {vv[0] - lse, vv[1] - lse, vv[2] - lse, vv[3] - lse};
        float4 ob = {vv[4] - lse, vv[5] - lse, vv[6] - lse, vv[7] - lse};
        *(float4*)(out + (size_t)n * 40 + 8 * l8)     = oa;
        *(float4*)(out + (size_t)n * 40 + 8 * l8 + 4) = ob;
    }
}

extern "C" void kernel_launch(void* const* d_in, const int* in_sizes, int n_in,
                              void* d_out, int out_size, void* d_ws, size_t ws_size,
                              hipStream_t stream) {
    const float* x    = (const float*)d_in[0];
    const int*   ei   = (const int*)d_in[1];
    const float* W1   = (const float*)d_in[2];
    const float* a1s  = (const float*)d_in[3];
    const float* a1d  = (const float*)d_in[4];
    const float* b1   = (const float*)d_in[5];
    const float* g1   = (const float*)d_in[6];
    const float* be1  = (const float*)d_in[7];
    const float* mn1  = (const float*)d_in[8];
    const float* vr1  = (const float*)d_in[9];
    const float* W2   = (const float*)d_in[10];
    const float* a2s  = (const float*)d_in[11];
    const float* a2d  = (const float*)d_in[12];
    const float* b2   = (const float*)d_in[13];
    float* out = (float*)d_out;

    const int N  = in_sizes[0] / 128;
    const int E  = in_sizes[1] / 2;
    const int Et = E + N;
    const int nCoarse = (N + COARSE_NPB - 1) >> COARSE_SHIFT;
    const int chunk   = (Et + NBLK - 1) / NBLK;

    char* p = (char*)d_ws;
    auto alloc = [&](size_t bytes) -> void* {
        void* r = (void*)p;
        p += (bytes + 255) & ~(size_t)255;
        return r;
    };
    int*      hist   = (int*)alloc((size_t)nCoarse * NBLK * 4);
    int*      cbase  = (int*)alloc((size_t)(nCoarse + 1) * 4);
    int*      offs   = (int*)alloc((size_t)(N + 1) * 4);
    unsigned* staged = (unsigned*)alloc((size_t)Et * 4);
    int*      csr    = (int*)alloc((size_t)Et * 4);
    unsigned* h1b    = (unsigned*)alloc((size_t)N * 64 * 4);
    float*    al1sv  = (float*)alloc((size_t)N * 2 * 4);
    float*    al1dv  = (float*)alloc((size_t)N * 2 * 4);
    unsigned* hbnb   = (unsigned*)alloc((size_t)N * 64 * 4);
    unsigned* h2b    = (unsigned*)alloc((size_t)N * 32 * 4);
    float*    al2sv  = (float*)alloc((size_t)N * 4);
    float*    al2dv  = (float*)alloc((size_t)N * 4);
    unsigned* gmax   = (unsigned*)alloc(4 * 4);
    float*    bnscale= (float*)alloc(128 * 4);
    float*    bnshift= (float*)alloc(128 * 4);
    (void)ws_size;

    hipMemsetAsync(gmax, 0, 16, stream);

    part_hist<<<NBLK, 256, 0, stream>>>(ei, E, Et, chunk, hist, nCoarse);
    csr_mid<<<1, 1024, 0, stream>>>(hist, cbase, nCoarse);
    part_scatter<<<NBLK, 256, 0, stream>>>(ei, E, Et, chunk, hist, staged, nCoarse);
    fine_place<<<nCoarse, 512, 0, stream>>>(staged, cbase, offs, csr, N, nCoarse);

    gemm1_tiled<<<(N + 127) / 128, 256, 0, stream>>>(x, W1, a1s, a1d, h1b, al1sv, al1dv, N);
    almax_kernel<2><<<64, 256, 0, stream>>>(al1sv, gmax, 0, N, b1, g1, be1, mn1, vr1, bnscale, bnshift);
    softagg1_kernel<<<(N + 3) / 4, 256, 0, stream>>>(offs, csr, h1b, al1sv, al1dv, gmax,
                                                     bnscale, bnshift, hbnb, N);

    gemm2_tiled<<<(N + 127) / 128, 256, 0, stream>>>(hbnb, W2, a2s, a2d, h2b, al2sv, al2dv, N);
    almax_kernel<1><<<64, 256, 0, stream>>>(al2sv, gmax, 2, N, nullptr, nullptr, nullptr, nullptr,
                                            nullptr, nullptr, nullptr);
    softagg2_kernel<<<(N + 3) / 4, 256, 0, stream>>>(offs, csr, h2b, al2sv, al2dv, gmax, b2, out, N);
}

// Round 13
// 241.294 us; speedup vs baseline: 1.0977x; 1.0977x over previous
//
#include <hip/hip_runtime.h>
#include <hip/hip_bf16.h>

#define NEG_SLOPE 0.2f
#define BN_EPS 1e-5f

#define NBLK 256
#define COARSE_SHIFT 9
#define COARSE_NPB 512

__device__ __forceinline__ float wred_sum(float v) {
    #pragma unroll
    for (int m = 32; m > 0; m >>= 1) v += __shfl_xor(v, m);
    return v;
}
__device__ __forceinline__ float wred_max(float v) {
    #pragma unroll
    for (int m = 32; m > 0; m >>= 1) v = fmaxf(v, __shfl_xor(v, m));
    return v;
}
__device__ __forceinline__ int wred_isum(int v) {
    #pragma unroll
    for (int m = 32; m > 0; m >>= 1) v += __shfl_xor(v, m);
    return v;
}
__device__ __forceinline__ float xor16_sum(float v) {
    #pragma unroll
    for (int m = 1; m < 16; m <<= 1) v += __shfl_xor(v, m);
    return v;
}

__device__ __forceinline__ unsigned pack_bf16(float a, float b) {
    __hip_bfloat162 t;
    t.x = __float2bfloat16(a);
    t.y = __float2bfloat16(b);
    return *(unsigned*)&t;
}
__device__ __forceinline__ float2 unpack_bf16(unsigned u) {
    __hip_bfloat162 t = *(__hip_bfloat162*)&u;
    return {__bfloat162float(t.x), __bfloat162float(t.y)};
}

__device__ __forceinline__ unsigned enc_ord(float f) {
    unsigned u = __float_as_uint(f);
    return (u & 0x80000000u) ? ~u : (u | 0x80000000u);
}
__device__ __forceinline__ float dec_ord(unsigned e) {
    unsigned u = (e & 0x80000000u) ? (e ^ 0x80000000u) : ~e;
    return __uint_as_float(u);
}

// ---- CSR build: per-block coarse histogram (LDS only) ----
__global__ __launch_bounds__(256) void part_hist(const int* __restrict__ ei, int E, int Et,
                                                 int chunk, int* __restrict__ hist, int nCoarse) {
    __shared__ int h[128];
    int b = blockIdx.x, t = threadIdx.x;
    if (t < 128) h[t] = 0;
    __syncthreads();
    int beg = b * chunk, end = min(beg + chunk, Et);
    for (int idx = beg + t; idx < end; idx += 256) {
        int d = (idx < E) ? ei[E + idx] : (idx - E);
        atomicAdd(&h[d >> COARSE_SHIFT], 1);
    }
    __syncthreads();
    if (t < nCoarse) hist[t * NBLK + b] = h[t];
}

// ---- fused: bucket totals + bucket scan + per-(bucket,block) scan ----
__global__ __launch_bounds__(1024) void csr_mid(int* __restrict__ hist,
                                                int* __restrict__ cbase, int nCoarse) {
    __shared__ int ctot_s[128];
    __shared__ int scn[128];
    __shared__ int cb_s[129];
    int t = threadIdx.x;
    int wv = t >> 6, ln = t & 63;
    if (t < 128) ctot_s[t] = 0;
    __syncthreads();
    for (int c = wv; c < nCoarse; c += 16) {
        int idx = c * NBLK + 4 * ln;
        int4 v = *(int4*)&hist[idx];
        int s = wred_isum(v.x + v.y + v.z + v.w);
        if (ln == 0) ctot_s[c] = s;
    }
    __syncthreads();
    int v0 = 0;
    if (t < 128) { v0 = ctot_s[t]; scn[t] = v0; }
    __syncthreads();
    for (int off = 1; off < 128; off <<= 1) {
        int u = (t >= off && t < 128) ? scn[t - off] : 0;
        __syncthreads();
        if (t < 128) scn[t] += u;
        __syncthreads();
    }
    if (t < 128) cb_s[t] = scn[t] - v0;
    if (t == 127) cb_s[128] = scn[127];
    __syncthreads();
    if (t <= nCoarse) cbase[t] = cb_s[t];
    for (int c = wv; c < nCoarse; c += 16) {
        int base = cb_s[c];
        int idx = c * NBLK + 4 * ln;
        int4 v = *(int4*)&hist[idx];
        int sl = v.x + v.y + v.z + v.w;
        int inc = sl;
        #pragma unroll
        for (int off = 1; off < 64; off <<= 1) {
            int u = __shfl_up(inc, off);
            if (ln >= off) inc += u;
        }
        int exc = inc - sl + base;
        int4 o;
        o.x = exc;
        o.y = exc + v.x;
        o.z = exc + v.x + v.y;
        o.w = exc + v.x + v.y + v.z;
        *(int4*)&hist[idx] = o;
    }
}

__global__ __launch_bounds__(256) void part_scatter(const int* __restrict__ ei, int E, int Et,
                                                    int chunk, const int* __restrict__ hist,
                                                    unsigned* __restrict__ staged, int nCoarse) {
    __shared__ int cur[128];
    int b = blockIdx.x, t = threadIdx.x;
    if (t < nCoarse) cur[t] = hist[t * NBLK + b];
    __syncthreads();
    int beg = b * chunk, end = min(beg + chunk, Et);
    for (int idx = beg + t; idx < end; idx += 256) {
        int s, d;
        if (idx < E) { s = ei[idx]; d = ei[E + idx]; }
        else         { s = idx - E; d = idx - E; }
        int c = d >> COARSE_SHIFT;
        int pos = atomicAdd(&cur[c], 1);
        staged[pos] = ((unsigned)s << COARSE_SHIFT) | (unsigned)(d & (COARSE_NPB - 1));
    }
}

__global__ __launch_bounds__(512) void fine_place(const unsigned* __restrict__ staged,
                                                  const int* __restrict__ cbase,
                                                  int* __restrict__ offs,
                                                  int* __restrict__ csr, int Nn, int nCoarse) {
    __shared__ int hcnt[COARSE_NPB];
    __shared__ int scn[COARSE_NPB];
    int b = blockIdx.x, t = threadIdx.x;
    int node0 = b << COARSE_SHIFT;
    int nloc = min(COARSE_NPB, Nn - node0);
    hcnt[t] = 0;
    __syncthreads();
    int ebeg = cbase[b], eend = cbase[b + 1];
    for (int p = ebeg + t; p < eend; p += 512) {
        atomicAdd(&hcnt[staged[p] & (COARSE_NPB - 1)], 1);
    }
    __syncthreads();
    int val = hcnt[t];
    scn[t] = val;
    __syncthreads();
    for (int off = 1; off < COARSE_NPB; off <<= 1) {
        int u = (t >= off) ? scn[t - off] : 0;
        __syncthreads();
        scn[t] += u;
        __syncthreads();
    }
    int exc = ebeg + scn[t] - val;
    if (t < nloc) offs[node0 + t] = exc;
    if (b == nCoarse - 1 && t == 0) offs[Nn] = eend;
    hcnt[t] = exc;
    __syncthreads();
    for (int p = ebeg + t; p < eend; p += 512) {
        unsigned v = staged[p];
        int pos = atomicAdd(&hcnt[v & (COARSE_NPB - 1)], 1);
        csr[pos] = (int)(v >> COARSE_SHIFT);
    }
}

// ---------------- Layer 1 GEMM (128x128 tile, 8x8 micro, transposed-A LDS) + fused al1 ----------------
__global__ __launch_bounds__(256) void gemm1_tiled(const float* __restrict__ x,
                                                   const float* __restrict__ W,
                                                   const float* __restrict__ a1s,
                                                   const float* __restrict__ a1d,
                                                   unsigned* __restrict__ h1b,
                                                   float* __restrict__ als,
                                                   float* __restrict__ ald, int Nn) {
    __shared__ float Ast[32][132];
    __shared__ float Bs[32][132];
    int t  = threadIdx.x;
    int tx = t & 15;
    int ty = t >> 4;
    int br = blockIdx.x * 128;

    float acc[8][8];
    #pragma unroll
    for (int i = 0; i < 8; ++i)
        #pragma unroll
        for (int j = 0; j < 8; ++j) acc[i][j] = 0.f;

    int k4   = t & 7;
    int rowA = t >> 3;

    for (int k0 = 0; k0 < 128; k0 += 32) {
        #pragma unroll
        for (int i = 0; i < 4; ++i) {
            int r  = rowA + 32 * i;
            int gr = min(br + r, Nn - 1);
            float4 v = *(const float4*)(x + (size_t)gr * 128 + k0 + 4 * k4);
            Ast[4 * k4 + 0][r] = v.x; Ast[4 * k4 + 1][r] = v.y;
            Ast[4 * k4 + 2][r] = v.z; Ast[4 * k4 + 3][r] = v.w;
        }
        #pragma unroll
        for (int i = 0; i < 4; ++i) {
            int f  = t + 256 * i;
            int kk = f >> 5, c4 = f & 31;
            *(float4*)&Bs[kk][4 * c4] = *(const float4*)(W + (size_t)(k0 + kk) * 128 + 4 * c4);
        }
        __syncthreads();
        #pragma unroll 8
        for (int kk = 0; kk < 32; ++kk) {
            float4 a0 = *(const float4*)&Ast[kk][8 * ty];
            float4 a1 = *(const float4*)&Ast[kk][8 * ty + 4];
            float4 b0 = *(const float4*)&Bs[kk][8 * tx];
            float4 b1 = *(const float4*)&Bs[kk][8 * tx + 4];
            float av[8] = {a0.x, a0.y, a0.z, a0.w, a1.x, a1.y, a1.z, a1.w};
            float bv[8] = {b0.x, b0.y, b0.z, b0.w, b1.x, b1.y, b1.z, b1.w};
            #pragma unroll
            for (int i = 0; i < 8; ++i)
                #pragma unroll
                for (int j = 0; j < 8; ++j) acc[i][j] += av[i] * bv[j];
        }
        __syncthreads();
    }

    float a_s[8], a_d[8];
    #pragma unroll
    for (int j = 0; j < 8; ++j) { a_s[j] = a1s[8 * tx + j]; a_d[j] = a1d[8 * tx + j]; }
    bool h0 = (tx < 8);

    #pragma unroll
    for (int i = 0; i < 8; ++i) {
        int r = br + 8 * ty + i;
        if (r < Nn) {
            uint4 pk;
            pk.x = pack_bf16(acc[i][0], acc[i][1]);
            pk.y = pack_bf16(acc[i][2], acc[i][3]);
            pk.z = pack_bf16(acc[i][4], acc[i][5]);
            pk.w = pack_bf16(acc[i][6], acc[i][7]);
            *(uint4*)(h1b + (size_t)r * 64 + 4 * tx) = pk;
        }
        float ps = 0.f, pd = 0.f;
        #pragma unroll
        for (int j = 0; j < 8; ++j) { ps += acc[i][j] * a_s[j]; pd += acc[i][j] * a_d[j]; }
        float s0 = xor16_sum(h0 ? ps : 0.f);
        float s1 = xor16_sum(h0 ? 0.f : ps);
        float d0 = xor16_sum(h0 ? pd : 0.f);
        float d1 = xor16_sum(h0 ? 0.f : pd);
        if (tx == 0 && r < Nn) {
            als[r * 2] = s0; als[r * 2 + 1] = s1;
            ald[r * 2] = d0; ald[r * 2 + 1] = d1;
        }
    }
}

// ---- global max of als per head + (block 0) BN scale/shift precompute ----
template <int H>
__global__ __launch_bounds__(256) void almax_kernel(const float* __restrict__ als,
                                                    unsigned* __restrict__ gmax, int off, int Nn,
                                                    const float* __restrict__ b1,
                                                    const float* __restrict__ g1,
                                                    const float* __restrict__ be1,
                                                    const float* __restrict__ mn1,
                                                    const float* __restrict__ vr1,
                                                    float* __restrict__ bnscale,
                                                    float* __restrict__ bnshift) {
    __shared__ float red[4][H];
    int t = threadIdx.x;
    if (bnscale && blockIdx.x == 0 && t < 128) {
        float sc = rsqrtf(vr1[t] + BN_EPS) * g1[t];
        bnscale[t] = sc;
        bnshift[t] = be1[t] + (b1[t] - mn1[t]) * sc;
    }
    float m[H];
    #pragma unroll
    for (int h = 0; h < H; ++h) m[h] = -1e30f;
    for (int n = blockIdx.x * 256 + t; n < Nn; n += gridDim.x * 256) {
        #pragma unroll
        for (int h = 0; h < H; ++h) m[h] = fmaxf(m[h], als[n * H + h]);
    }
    #pragma unroll
    for (int h = 0; h < H; ++h) m[h] = wred_max(m[h]);
    int wid = t >> 6;
    if ((t & 63) == 0) {
        #pragma unroll
        for (int h = 0; h < H; ++h) red[wid][h] = m[h];
    }
    __syncthreads();
    if (t == 0) {
        #pragma unroll
        for (int h = 0; h < H; ++h) {
            float mm = fmaxf(fmaxf(red[0][h], red[1][h]), fmaxf(red[2][h], red[3][h]));
            atomicMax(&gmax[off + h], enc_ord(mm));
        }
    }
}

// ---------------- softagg1: 4 nodes/wave, 16 lanes/node, lane owns 8 cols (no acc shuffles) ----------------
__global__ __launch_bounds__(256) void softagg1_kernel(const int* __restrict__ offs, const int* __restrict__ csr,
                            const unsigned* __restrict__ h1b,
                            const float* __restrict__ als, const float* __restrict__ ald,
                            const unsigned* __restrict__ gmax,
                            const float* __restrict__ bnscale, const float* __restrict__ bnshift,
                            unsigned* __restrict__ hbnb, int Nn) {
    __shared__ int   sh_s[4][4][16];
    __shared__ float sh_e[4][4][2][16];
    int wid = threadIdx.x >> 6, lane = threadIdx.x & 63;
    int g = lane >> 4;            // node group 0..3
    int l = lane & 15;            // owns cols 8l..8l+7 (uint4 index 4l)
    int head = l >> 3;
    int n = blockIdx.x * 16 + wid * 4 + g;
    if (n >= Nn) return;
    int b = offs[n], e = offs[n + 1];
    float2 aldn = *(const float2*)(ald + (size_t)n * 2);
    float bd0 = dec_ord(gmax[0]) + aldn.x; bd0 = (bd0 > 0.f) ? bd0 : NEG_SLOPE * bd0;
    float bd1 = dec_ord(gmax[1]) + aldn.y; bd1 = (bd1 > 0.f) ? bd1 : NEG_SLOPE * bd1;

    float acc[8];
    #pragma unroll
    for (int j = 0; j < 8; ++j) acc[j] = 0.f;
    float den0 = 0.f, den1 = 0.f;

    for (int base = b; base < e; base += 16) {
        int cnt = min(16, e - base);
        // phase 1: one lane per edge (16-wide matches avg degree ~17)
        int   s1 = 0;
        float e0r = 0.f, e1r = 0.f;
        if (l < cnt) {
            s1 = csr[base + l];
            float2 as = *(const float2*)(als + (size_t)s1 * 2);
            float l0 = as.x + aldn.x; l0 = (l0 > 0.f) ? l0 : NEG_SLOPE * l0;
            float l1 = as.y + aldn.y; l1 = (l1 > 0.f) ? l1 : NEG_SLOPE * l1;
            e0r = __expf(l0 - bd0);
            e1r = __expf(l1 - bd1);
            den0 += e0r; den1 += e1r;
        }
        sh_s[wid][g][l]    = s1;
        sh_e[wid][g][0][l] = e0r;
        sh_e[wid][g][1][l] = e1r;
        // phase 2: lane loads its uint4 of each edge's row; 2 edges in flight
        int i = 0;
        for (; i + 1 < cnt; i += 2) {
            int   sA  = sh_s[wid][g][i];
            int   sB  = sh_s[wid][g][i + 1];
            float evA = sh_e[wid][g][head][i];
            float evB = sh_e[wid][g][head][i + 1];
            uint4 vA = *(const uint4*)(h1b + (size_t)sA * 64 + 4 * l);
            uint4 vB = *(const uint4*)(h1b + (size_t)sB * 64 + 4 * l);
            float2 f;
            f = unpack_bf16(vA.x); acc[0] += f.x * evA; acc[1] += f.y * evA;
            f = unpack_bf16(vA.y); acc[2] += f.x * evA; acc[3] += f.y * evA;
            f = unpack_bf16(vA.z); acc[4] += f.x * evA; acc[5] += f.y * evA;
            f = unpack_bf16(vA.w); acc[6] += f.x * evA; acc[7] += f.y * evA;
            f = unpack_bf16(vB.x); acc[0] += f.x * evB; acc[1] += f.y * evB;
            f = unpack_bf16(vB.y); acc[2] += f.x * evB; acc[3] += f.y * evB;
            f = unpack_bf16(vB.z); acc[4] += f.x * evB; acc[5] += f.y * evB;
            f = unpack_bf16(vB.w); acc[6] += f.x * evB; acc[7] += f.y * evB;
        }
        if (i < cnt) {
            int   s  = sh_s[wid][g][i];
            float ev = sh_e[wid][g][head][i];
            uint4 v = *(const uint4*)(h1b + (size_t)s * 64 + 4 * l);
            float2 f;
            f = unpack_bf16(v.x); acc[0] += f.x * ev; acc[1] += f.y * ev;
            f = unpack_bf16(v.y); acc[2] += f.x * ev; acc[3] += f.y * ev;
            f = unpack_bf16(v.z); acc[4] += f.x * ev; acc[5] += f.y * ev;
            f = unpack_bf16(v.w); acc[6] += f.x * ev; acc[7] += f.y * ev;
        }
    }
    // reduce dens within the 16-lane group
    #pragma unroll
    for (int m = 1; m < 16; m <<= 1) {
        den0 += __shfl_xor(den0, m);
        den1 += __shfl_xor(den1, m);
    }
    float inv = 1.f / ((head ? den1 : den0) + 1e-16f);
    int c = 8 * l;
    float4 sa = *(const float4*)(bnscale + c), sb = *(const float4*)(bnscale + c + 4);
    float4 ha = *(const float4*)(bnshift + c), hb = *(const float4*)(bnshift + c + 4);
    float o0 = fmaxf(acc[0] * inv * sa.x + ha.x, 0.f);
    float o1 = fmaxf(acc[1] * inv * sa.y + ha.y, 0.f);
    float o2 = fmaxf(acc[2] * inv * sa.z + ha.z, 0.f);
    float o3 = fmaxf(acc[3] * inv * sa.w + ha.w, 0.f);
    float o4 = fmaxf(acc[4] * inv * sb.x + hb.x, 0.f);
    float o5 = fmaxf(acc[5] * inv * sb.y + hb.y, 0.f);
    float o6 = fmaxf(acc[6] * inv * sb.z + hb.z, 0.f);
    float o7 = fmaxf(acc[7] * inv * sb.w + hb.w, 0.f);
    uint4 pk = {pack_bf16(o0, o1), pack_bf16(o2, o3), pack_bf16(o4, o5), pack_bf16(o6, o7)};
    *(uint4*)(hbnb + (size_t)n * 64 + 4 * l) = pk;
}

// ---------------- Layer 2 GEMM (A from bf16 hbnb) + fused al2; h2b rows = 20 uints (40 cols) ----------------
__global__ __launch_bounds__(256) void gemm2_tiled(const unsigned* __restrict__ hbnb,
                                                   const float* __restrict__ W2,
                                                   const float* __restrict__ a2s,
                                                   const float* __restrict__ a2d,
                                                   unsigned* __restrict__ h2b,
                                                   float* __restrict__ als, float* __restrict__ ald,
                                                   int Nn) {
    __shared__ float Ast[32][132];
    __shared__ float Bs[32][68];
    int t  = threadIdx.x;
    int tx = t & 15;
    int ty = t >> 4;
    int br = blockIdx.x * 128;

    float as4[4], ad4[4];
    #pragma unroll
    for (int j = 0; j < 4; ++j) {
        int c = 4 * tx + j;
        as4[j] = (c < 40) ? a2s[c] : 0.f;
        ad4[j] = (c < 40) ? a2d[c] : 0.f;
    }

    float acc[8][4];
    #pragma unroll
    for (int i = 0; i < 8; ++i)
        #pragma unroll
        for (int j = 0; j < 4; ++j) acc[i][j] = 0.f;

    int k4   = t & 7;
    int rowA = t >> 3;

    for (int k0 = 0; k0 < 128; k0 += 32) {
        #pragma unroll
        for (int i = 0; i < 4; ++i) {
            int r  = rowA + 32 * i;
            int gr = min(br + r, Nn - 1);
            uint2 v2 = *(const uint2*)(hbnb + (size_t)gr * 64 + (k0 >> 1) + 2 * k4);
            float2 f0 = unpack_bf16(v2.x), f1 = unpack_bf16(v2.y);
            Ast[4 * k4 + 0][r] = f0.x; Ast[4 * k4 + 1][r] = f0.y;
            Ast[4 * k4 + 2][r] = f1.x; Ast[4 * k4 + 3][r] = f1.y;
        }
        #pragma unroll
        for (int i = 0; i < 2; ++i) {
            int f  = t + 256 * i;
            int kk = f >> 4, c4 = f & 15;
            float4 v = {0.f, 0.f, 0.f, 0.f};
            if (c4 < 10) v = *(const float4*)(W2 + (size_t)(k0 + kk) * 40 + 4 * c4);
            *(float4*)&Bs[kk][4 * c4] = v;
        }
        __syncthreads();
        #pragma unroll 8
        for (int kk = 0; kk < 32; ++kk) {
            float4 a0 = *(const float4*)&Ast[kk][8 * ty];
            float4 a1 = *(const float4*)&Ast[kk][8 * ty + 4];
            float4 b0 = *(const float4*)&Bs[kk][4 * tx];
            float av[8] = {a0.x, a0.y, a0.z, a0.w, a1.x, a1.y, a1.z, a1.w};
            #pragma unroll
            for (int i = 0; i < 8; ++i) {
                acc[i][0] += av[i] * b0.x; acc[i][1] += av[i] * b0.y;
                acc[i][2] += av[i] * b0.z; acc[i][3] += av[i] * b0.w;
            }
        }
        __syncthreads();
    }

    #pragma unroll
    for (int i = 0; i < 8; ++i) {
        int r = br + 8 * ty + i;
        if (r < Nn && tx < 10) {
            uint2 pk = {pack_bf16(acc[i][0], acc[i][1]), pack_bf16(acc[i][2], acc[i][3])};
            *(uint2*)(h2b + (size_t)r * 20 + 2 * tx) = pk;
        }
        float ps = acc[i][0] * as4[0] + acc[i][1] * as4[1] + acc[i][2] * as4[2] + acc[i][3] * as4[3];
        float pd = acc[i][0] * ad4[0] + acc[i][1] * ad4[1] + acc[i][2] * ad4[2] + acc[i][3] * ad4[3];
        float sS = xor16_sum(ps);
        float sD = xor16_sum(pd);
        if (tx == 0 && r < Nn) { als[r] = sS; ald[r] = sD; }
    }
}

// ---------------- softagg2: 8 nodes/wave, 8 lanes/node, lane owns 8 cols (stride-20 h2b) ----------------
__global__ __launch_bounds__(256) void softagg2_kernel(const int* __restrict__ offs, const int* __restrict__ csr,
                            const unsigned* __restrict__ h2b,
                            const float* __restrict__ als, const float* __restrict__ ald,
                            const unsigned* __restrict__ gmax,
                            const float* __restrict__ b2,
                            float* __restrict__ out, int Nn) {
    __shared__ int   sh_s[4][8][8];
    __shared__ float sh_ev[4][8][8];
    int wid = threadIdx.x >> 6, lane = threadIdx.x & 63;
    int g = lane >> 3;            // node group 0..7
    int l = lane & 7;             // owns cols 8l..8l+7 (valid l<5)
    int n = blockIdx.x * 32 + wid * 8 + g;
    if (n >= Nn) return;
    int b = offs[n], e = offs[n + 1];
    float aldn = ald[n];
    float bound = dec_ord(gmax[2]) + aldn;
    bound = (bound > 0.f) ? bound : NEG_SLOPE * bound;

    float acc[8];
    #pragma unroll
    for (int j = 0; j < 8; ++j) acc[j] = 0.f;
    float den = 0.f;

    for (int base = b; base < e; base += 8) {
        int cnt = min(8, e - base);
        int   s1 = 0;
        float evr = 0.f;
        if (l < cnt) {
            s1 = csr[base + l];
            float lv = als[s1] + aldn;
            lv = (lv > 0.f) ? lv : NEG_SLOPE * lv;
            evr = __expf(lv - bound);
            den += evr;
        }
        sh_s[wid][g][l]  = s1;
        sh_ev[wid][g][l] = evr;
        if (l < 5) {
            int i = 0;
            for (; i + 1 < cnt; i += 2) {
                int   sA  = sh_s[wid][g][i];
                int   sB  = sh_s[wid][g][i + 1];
                float evA = sh_ev[wid][g][i];
                float evB = sh_ev[wid][g][i + 1];
                uint4 vA = *(const uint4*)(h2b + (size_t)sA * 20 + 4 * l);
                uint4 vB = *(const uint4*)(h2b + (size_t)sB * 20 + 4 * l);
                float2 f;
                f = unpack_bf16(vA.x); acc[0] += f.x * evA; acc[1] += f.y * evA;
                f = unpack_bf16(vA.y); acc[2] += f.x * evA; acc[3] += f.y * evA;
                f = unpack_bf16(vA.z); acc[4] += f.x * evA; acc[5] += f.y * evA;
                f = unpack_bf16(vA.w); acc[6] += f.x * evA; acc[7] += f.y * evA;
                f = unpack_bf16(vB.x); acc[0] += f.x * evB; acc[1] += f.y * evB;
                f = unpack_bf16(vB.y); acc[2] += f.x * evB; acc[3] += f.y * evB;
                f = unpack_bf16(vB.z); acc[4] += f.x * evB; acc[5] += f.y * evB;
                f = unpack_bf16(vB.w); acc[6] += f.x * evB; acc[7] += f.y * evB;
            }
            if (i < cnt) {
                int   s  = sh_s[wid][g][i];
                float ev = sh_ev[wid][g][i];
                uint4 v = *(const uint4*)(h2b + (size_t)s * 20 + 4 * l);
                float2 f;
                f = unpack_bf16(v.x); acc[0] += f.x * ev; acc[1] += f.y * ev;
                f = unpack_bf16(v.y); acc[2] += f.x * ev; acc[3] += f.y * ev;
                f = unpack_bf16(v.z); acc[4] += f.x * ev; acc[5] += f.y * ev;
                f = unpack_bf16(v.w); acc[6] += f.x * ev; acc[7] += f.y * ev;
            }
        }
    }
    // den over the 8-lane group
    #pragma unroll
    for (int m = 1; m < 8; m <<= 1) den += __shfl_xor(den, m);
    float inv = 1.f / (den + 1e-16f);
    bool valid = (l < 5);
    float vv[8];
    float lmax = -1e30f;
    if (valid) {
        int c = 8 * l;
        #pragma unroll
        for (int j = 0; j < 8; ++j) {
            vv[j] = acc[j] * inv + b2[c + j];
            lmax = fmaxf(lmax, vv[j]);
        }
    }
    float m = lmax;
    #pragma unroll
    for (int mm = 1; mm < 8; mm <<= 1) m = fmaxf(m, __shfl_xor(m, mm));
    float es = 0.f;
    if (valid) {
        #pragma unroll
        for (int j = 0; j < 8; ++j) es += __expf(vv[j] - m);
    }
    #pragma unroll
    for (int mm = 1; mm < 8; mm <<= 1) es += __shfl_xor(es, mm);
    float lse = m + logf(es);
    if (valid) {
        float4 oa = {vv[0] - lse, vv[1] - lse, vv[2] - lse, vv[3] - lse};
        float4 ob = {vv[4] - lse, vv[5] - lse, vv[6] - lse, vv[7] - lse};
        *(float4*)(out + (size_t)n * 40 + 8 * l)     = oa;
        *(float4*)(out + (size_t)n * 40 + 8 * l + 4) = ob;
    }
}

extern "C" void kernel_launch(void* const* d_in, const int* in_sizes, int n_in,
                              void* d_out, int out_size, void* d_ws, size_t ws_size,
                              hipStream_t stream) {
    const float* x    = (const float*)d_in[0];
    const int*   ei   = (const int*)d_in[1];
    const float* W1   = (const float*)d_in[2];
    const float* a1s  = (const float*)d_in[3];
    const float* a1d  = (const float*)d_in[4];
    const float* b1   = (const float*)d_in[5];
    const float* g1   = (const float*)d_in[6];
    const float* be1  = (const float*)d_in[7];
    const float* mn1  = (const float*)d_in[8];
    const float* vr1  = (const float*)d_in[9];
    const float* W2   = (const float*)d_in[10];
    const float* a2s  = (const float*)d_in[11];
    const float* a2d  = (const float*)d_in[12];
    const float* b2   = (const float*)d_in[13];
    float* out = (float*)d_out;

    const int N  = in_sizes[0] / 128;
    const int E  = in_sizes[1] / 2;
    const int Et = E + N;
    const int nCoarse = (N + COARSE_NPB - 1) >> COARSE_SHIFT;
    const int chunk   = (Et + NBLK - 1) / NBLK;

    char* p = (char*)d_ws;
    auto alloc = [&](size_t bytes) -> void* {
        void* r = (void*)p;
        p += (bytes + 255) & ~(size_t)255;
        return r;
    };
    int*      hist   = (int*)alloc((size_t)nCoarse * NBLK * 4);
    int*      cbase  = (int*)alloc((size_t)(nCoarse + 1) * 4);
    int*      offs   = (int*)alloc((size_t)(N + 1) * 4);
    unsigned* staged = (unsigned*)alloc((size_t)Et * 4);
    int*      csr    = (int*)alloc((size_t)Et * 4);
    unsigned* h1b    = (unsigned*)alloc((size_t)N * 64 * 4);
    float*    al1sv  = (float*)alloc((size_t)N * 2 * 4);
    float*    al1dv  = (float*)alloc((size_t)N * 2 * 4);
    unsigned* hbnb   = (unsigned*)alloc((size_t)N * 64 * 4);
    unsigned* h2b    = (unsigned*)alloc((size_t)N * 20 * 4);
    float*    al2sv  = (float*)alloc((size_t)N * 4);
    float*    al2dv  = (float*)alloc((size_t)N * 4);
    unsigned* gmax   = (unsigned*)alloc(4 * 4);
    float*    bnscale= (float*)alloc(128 * 4);
    float*    bnshift= (float*)alloc(128 * 4);
    (void)ws_size;

    hipMemsetAsync(gmax, 0, 16, stream);

    part_hist<<<NBLK, 256, 0, stream>>>(ei, E, Et, chunk, hist, nCoarse);
    csr_mid<<<1, 1024, 0, stream>>>(hist, cbase, nCoarse);
    part_scatter<<<NBLK, 256, 0, stream>>>(ei, E, Et, chunk, hist, staged, nCoarse);
    fine_place<<<nCoarse, 512, 0, stream>>>(staged, cbase, offs, csr, N, nCoarse);

    gemm1_tiled<<<(N + 127) / 128, 256, 0, stream>>>(x, W1, a1s, a1d, h1b, al1sv, al1dv, N);
    almax_kernel<2><<<64, 256, 0, stream>>>(al1sv, gmax, 0, N, b1, g1, be1, mn1, vr1, bnscale, bnshift);
    softagg1_kernel<<<(N + 15) / 16, 256, 0, stream>>>(offs, csr, h1b, al1sv, al1dv, gmax,
                                                       bnscale, bnshift, hbnb, N);

    gemm2_tiled<<<(N + 127) / 128, 256, 0, stream>>>(hbnb, W2, a2s, a2d, h2b, al2sv, al2dv, N);
    almax_kernel<1><<<64, 256, 0, stream>>>(al2sv, gmax, 2, N, nullptr, nullptr, nullptr, nullptr,
                                            nullptr, nullptr, nullptr);
    softagg2_kernel<<<(N + 31) / 32, 256, 0, stream>>>(offs, csr, h2b, al2sv, al2dv, gmax, b2, out, N);
}

// Round 14
// 225.233 us; speedup vs baseline: 1.1759x; 1.0713x over previous
//
#include <hip/hip_runtime.h>
#include <hip/hip_bf16.h>

#define NEG_SLOPE 0.2f
#define BN_EPS 1e-5f

#define NBLK 256
#define COARSE_SHIFT 9
#define COARSE_NPB 512

typedef __attribute__((ext_vector_type(8))) short s8v;   // 8 bf16 (4 VGPRs)
typedef __attribute__((ext_vector_type(4))) float f4v;   // 4 fp32 acc

__device__ __forceinline__ float wred_sum(float v) {
    #pragma unroll
    for (int m = 32; m > 0; m >>= 1) v += __shfl_xor(v, m);
    return v;
}
__device__ __forceinline__ float wred_max(float v) {
    #pragma unroll
    for (int m = 32; m > 0; m >>= 1) v = fmaxf(v, __shfl_xor(v, m));
    return v;
}
__device__ __forceinline__ int wred_isum(int v) {
    #pragma unroll
    for (int m = 32; m > 0; m >>= 1) v += __shfl_xor(v, m);
    return v;
}
__device__ __forceinline__ float xor16_sum(float v) {
    #pragma unroll
    for (int m = 1; m < 16; m <<= 1) v += __shfl_xor(v, m);
    return v;
}

__device__ __forceinline__ unsigned pack_bf16(float a, float b) {
    __hip_bfloat162 t;
    t.x = __float2bfloat16(a);
    t.y = __float2bfloat16(b);
    return *(unsigned*)&t;
}
__device__ __forceinline__ float2 unpack_bf16(unsigned u) {
    __hip_bfloat162 t = *(__hip_bfloat162*)&u;
    return {__bfloat162float(t.x), __bfloat162float(t.y)};
}
__device__ __forceinline__ short bf16s(float f) {
    __hip_bfloat16 h = __float2bfloat16(f);
    return *(short*)&h;
}

__device__ __forceinline__ unsigned enc_ord(float f) {
    unsigned u = __float_as_uint(f);
    return (u & 0x80000000u) ? ~u : (u | 0x80000000u);
}
__device__ __forceinline__ float dec_ord(unsigned e) {
    unsigned u = (e & 0x80000000u) ? (e ^ 0x80000000u) : ~e;
    return __uint_as_float(u);
}

// ---- CSR build: per-block coarse histogram (LDS only); block 0 zeroes gmax ----
__global__ __launch_bounds__(256) void part_hist(const int* __restrict__ ei, int E, int Et,
                                                 int chunk, int* __restrict__ hist, int nCoarse,
                                                 unsigned* __restrict__ gmax) {
    __shared__ int h[128];
    int b = blockIdx.x, t = threadIdx.x;
    if (b == 0 && t < 4) gmax[t] = 0u;   // encoded 0 < all reals
    if (t < 128) h[t] = 0;
    __syncthreads();
    int beg = b * chunk, end = min(beg + chunk, Et);
    for (int idx = beg + t; idx < end; idx += 256) {
        int d = (idx < E) ? ei[E + idx] : (idx - E);
        atomicAdd(&h[d >> COARSE_SHIFT], 1);
    }
    __syncthreads();
    if (t < nCoarse) hist[t * NBLK + b] = h[t];
}

// ---- fused: bucket totals + bucket scan + per-(bucket,block) scan ----
__global__ __launch_bounds__(1024) void csr_mid(int* __restrict__ hist,
                                                int* __restrict__ cbase, int nCoarse) {
    __shared__ int ctot_s[128];
    __shared__ int scn[128];
    __shared__ int cb_s[129];
    int t = threadIdx.x;
    int wv = t >> 6, ln = t & 63;
    if (t < 128) ctot_s[t] = 0;
    __syncthreads();
    for (int c = wv; c < nCoarse; c += 16) {
        int idx = c * NBLK + 4 * ln;
        int4 v = *(int4*)&hist[idx];
        int s = wred_isum(v.x + v.y + v.z + v.w);
        if (ln == 0) ctot_s[c] = s;
    }
    __syncthreads();
    int v0 = 0;
    if (t < 128) { v0 = ctot_s[t]; scn[t] = v0; }
    __syncthreads();
    for (int off = 1; off < 128; off <<= 1) {
        int u = (t >= off && t < 128) ? scn[t - off] : 0;
        __syncthreads();
        if (t < 128) scn[t] += u;
        __syncthreads();
    }
    if (t < 128) cb_s[t] = scn[t] - v0;
    if (t == 127) cb_s[128] = scn[127];
    __syncthreads();
    if (t <= nCoarse) cbase[t] = cb_s[t];
    for (int c = wv; c < nCoarse; c += 16) {
        int base = cb_s[c];
        int idx = c * NBLK + 4 * ln;
        int4 v = *(int4*)&hist[idx];
        int sl = v.x + v.y + v.z + v.w;
        int inc = sl;
        #pragma unroll
        for (int off = 1; off < 64; off <<= 1) {
            int u = __shfl_up(inc, off);
            if (ln >= off) inc += u;
        }
        int exc = inc - sl + base;
        int4 o;
        o.x = exc;
        o.y = exc + v.x;
        o.z = exc + v.x + v.y;
        o.w = exc + v.x + v.y + v.z;
        *(int4*)&hist[idx] = o;
    }
}

__global__ __launch_bounds__(256) void part_scatter(const int* __restrict__ ei, int E, int Et,
                                                    int chunk, const int* __restrict__ hist,
                                                    unsigned* __restrict__ staged, int nCoarse) {
    __shared__ int cur[128];
    int b = blockIdx.x, t = threadIdx.x;
    if (t < nCoarse) cur[t] = hist[t * NBLK + b];
    __syncthreads();
    int beg = b * chunk, end = min(beg + chunk, Et);
    for (int idx = beg + t; idx < end; idx += 256) {
        int s, d;
        if (idx < E) { s = ei[idx]; d = ei[E + idx]; }
        else         { s = idx - E; d = idx - E; }
        int c = d >> COARSE_SHIFT;
        int pos = atomicAdd(&cur[c], 1);
        staged[pos] = ((unsigned)s << COARSE_SHIFT) | (unsigned)(d & (COARSE_NPB - 1));
    }
}

__global__ __launch_bounds__(512) void fine_place(const unsigned* __restrict__ staged,
                                                  const int* __restrict__ cbase,
                                                  int* __restrict__ offs,
                                                  int* __restrict__ csr, int Nn, int nCoarse) {
    __shared__ int hcnt[COARSE_NPB];
    __shared__ int scn[COARSE_NPB];
    int b = blockIdx.x, t = threadIdx.x;
    int node0 = b << COARSE_SHIFT;
    int nloc = min(COARSE_NPB, Nn - node0);
    hcnt[t] = 0;
    __syncthreads();
    int ebeg = cbase[b], eend = cbase[b + 1];
    for (int p = ebeg + t; p < eend; p += 512) {
        atomicAdd(&hcnt[staged[p] & (COARSE_NPB - 1)], 1);
    }
    __syncthreads();
    int val = hcnt[t];
    scn[t] = val;
    __syncthreads();
    for (int off = 1; off < COARSE_NPB; off <<= 1) {
        int u = (t >= off) ? scn[t - off] : 0;
        __syncthreads();
        scn[t] += u;
        __syncthreads();
    }
    int exc = ebeg + scn[t] - val;
    if (t < nloc) offs[node0 + t] = exc;
    if (b == nCoarse - 1 && t == 0) offs[Nn] = eend;
    hcnt[t] = exc;
    __syncthreads();
    for (int p = ebeg + t; p < eend; p += 512) {
        unsigned v = staged[p];
        int pos = atomicAdd(&hcnt[v & (COARSE_NPB - 1)], 1);
        csr[pos] = (int)(v >> COARSE_SHIFT);
    }
}

// ---------------- Layer 1 GEMM via bf16 MFMA (16x16x32) + fused al1 ----------------
// Block: 256 thr = 4 waves; wave w handles rows br+16w..+15, all 128 cols (8 col-tiles).
// W fragments precomputed in LDS (lane-consecutive 16B -> conflict-free ds_read_b128).
__global__ __launch_bounds__(256) void gemm1_mfma(const float* __restrict__ x,
                                                  const float* __restrict__ W,
                                                  const float* __restrict__ a1s,
                                                  const float* __restrict__ a1d,
                                                  unsigned* __restrict__ h1b,
                                                  float* __restrict__ als,
                                                  float* __restrict__ ald, int Nn) {
    __shared__ __align__(16) char smem[33792];   // fragtab (32768B) then reused as lout (33792B)
    short* fragtab = (short*)smem;
    float* lout    = (float*)smem;

    int t = threadIdx.x;
    int br = blockIdx.x * 64;

    // build W frag table: slot s=(ct*4+kc)*64+lane holds B[k=kc*32+quad*8+j][c=ct*16+n]
    #pragma unroll
    for (int i = 0; i < 8; ++i) {
        int s   = t + 256 * i;        // 0..2047
        int grp = s >> 6;             // ct*4+kc
        int ls  = s & 63;
        int ct = grp >> 2, kc = grp & 3;
        int nn = ls & 15, quad = ls >> 4;
        int kb = kc * 32 + quad * 8;
        int cc = ct * 16 + nn;
        #pragma unroll
        for (int j = 0; j < 8; ++j)
            fragtab[s * 8 + j] = bf16s(W[(size_t)(kb + j) * 128 + cc]);
    }
    __syncthreads();

    int w    = t >> 6;
    int lane = t & 63;
    int nn   = lane & 15;
    int quad = lane >> 4;
    int rowbase = br + w * 16;
    int arow = min(rowbase + nn, Nn - 1);
    const float* xr = x + (size_t)arow * 128;

    f4v acc[8];
    #pragma unroll
    for (int ct = 0; ct < 8; ++ct) acc[ct] = (f4v){0.f, 0.f, 0.f, 0.f};

    #pragma unroll
    for (int kc = 0; kc < 4; ++kc) {
        float4 v0 = *(const float4*)(xr + kc * 32 + quad * 8);
        float4 v1 = *(const float4*)(xr + kc * 32 + quad * 8 + 4);
        union { s8v s; uint4 u; } A;
        A.u.x = pack_bf16(v0.x, v0.y); A.u.y = pack_bf16(v0.z, v0.w);
        A.u.z = pack_bf16(v1.x, v1.y); A.u.w = pack_bf16(v1.z, v1.w);
        #pragma unroll
        for (int ct = 0; ct < 8; ++ct) {
            s8v B = *(s8v*)(fragtab + (size_t)((ct * 4 + kc) * 64 + lane) * 8);
            acc[ct] = __builtin_amdgcn_mfma_f32_16x16x32_bf16(A.s, B, acc[ct], 0, 0, 0);
        }
    }

    // fused al1: row-dot with a1s/a1d; lane's cols are ct*16+nn; head0 = ct<4
    float s_c[8], d_c[8];
    #pragma unroll
    for (int ct = 0; ct < 8; ++ct) {
        s_c[ct] = a1s[ct * 16 + nn];
        d_c[ct] = a1d[ct * 16 + nn];
    }
    #pragma unroll
    for (int reg = 0; reg < 4; ++reg) {
        float ps0 = 0.f, pd0 = 0.f, ps1 = 0.f, pd1 = 0.f;
        #pragma unroll
        for (int ct = 0; ct < 4; ++ct) { ps0 += acc[ct][reg] * s_c[ct]; pd0 += acc[ct][reg] * d_c[ct]; }
        #pragma unroll
        for (int ct = 4; ct < 8; ++ct) { ps1 += acc[ct][reg] * s_c[ct]; pd1 += acc[ct][reg] * d_c[ct]; }
        ps0 = xor16_sum(ps0); pd0 = xor16_sum(pd0);
        ps1 = xor16_sum(ps1); pd1 = xor16_sum(pd1);
        int r = rowbase + quad * 4 + reg;
        if (nn == 0 && r < Nn) {
            als[(size_t)r * 2]     = ps0;
            als[(size_t)r * 2 + 1] = ps1;
            ald[(size_t)r * 2]     = pd0;
            ald[(size_t)r * 2 + 1] = pd1;
        }
    }

    // h1b write via LDS transpose (repurpose fragtab region)
    __syncthreads();
    #pragma unroll
    for (int ct = 0; ct < 8; ++ct)
        #pragma unroll
        for (int reg = 0; reg < 4; ++reg)
            lout[w * 2112 + (quad * 4 + reg) * 132 + ct * 16 + nn] = acc[ct][reg];
    // intra-wave LDS write->read is program-ordered; no barrier needed (each wave reads own region)
    int row_l = lane >> 2;
    int ch    = lane & 3;
    int r = rowbase + row_l;
    if (r < Nn) {
        const float* src = lout + w * 2112 + row_l * 132 + ch * 32;
        #pragma unroll
        for (int i = 0; i < 4; ++i) {
            uint4 pk = {pack_bf16(src[8 * i + 0], src[8 * i + 1]),
                        pack_bf16(src[8 * i + 2], src[8 * i + 3]),
                        pack_bf16(src[8 * i + 4], src[8 * i + 5]),
                        pack_bf16(src[8 * i + 6], src[8 * i + 7])};
            *(uint4*)(h1b + (size_t)r * 64 + ch * 16 + i * 4) = pk;
        }
    }
}

// ---- global max of als per head + (block 0) BN scale/shift precompute ----
template <int H>
__global__ __launch_bounds__(256) void almax_kernel(const float* __restrict__ als,
                                                    unsigned* __restrict__ gmax, int off, int Nn,
                                                    const float* __restrict__ b1,
                                                    const float* __restrict__ g1,
                                                    const float* __restrict__ be1,
                                                    const float* __restrict__ mn1,
                                                    const float* __restrict__ vr1,
                                                    float* __restrict__ bnscale,
                                                    float* __restrict__ bnshift) {
    __shared__ float red[4][H];
    int t = threadIdx.x;
    if (bnscale && blockIdx.x == 0 && t < 128) {
        float sc = rsqrtf(vr1[t] + BN_EPS) * g1[t];
        bnscale[t] = sc;
        bnshift[t] = be1[t] + (b1[t] - mn1[t]) * sc;
    }
    float m[H];
    #pragma unroll
    for (int h = 0; h < H; ++h) m[h] = -1e30f;
    for (int n = blockIdx.x * 256 + t; n < Nn; n += gridDim.x * 256) {
        #pragma unroll
        for (int h = 0; h < H; ++h) m[h] = fmaxf(m[h], als[n * H + h]);
    }
    #pragma unroll
    for (int h = 0; h < H; ++h) m[h] = wred_max(m[h]);
    int wid = t >> 6;
    if ((t & 63) == 0) {
        #pragma unroll
        for (int h = 0; h < H; ++h) red[wid][h] = m[h];
    }
    __syncthreads();
    if (t == 0) {
        #pragma unroll
        for (int h = 0; h < H; ++h) {
            float mm = fmaxf(fmaxf(red[0][h], red[1][h]), fmaxf(red[2][h], red[3][h]));
            atomicMax(&gmax[off + h], enc_ord(mm));
        }
    }
}

// ---------------- softagg1: 4 nodes/wave, 16 lanes/node, lane owns 8 cols ----------------
__global__ __launch_bounds__(256) void softagg1_kernel(const int* __restrict__ offs, const int* __restrict__ csr,
                            const unsigned* __restrict__ h1b,
                            const float* __restrict__ als, const float* __restrict__ ald,
                            const unsigned* __restrict__ gmax,
                            const float* __restrict__ bnscale, const float* __restrict__ bnshift,
                            unsigned* __restrict__ hbnb, int Nn) {
    __shared__ int   sh_s[4][4][16];
    __shared__ float sh_e[4][4][2][16];
    int wid = threadIdx.x >> 6, lane = threadIdx.x & 63;
    int g = lane >> 4;
    int l = lane & 15;
    int head = l >> 3;
    int n = blockIdx.x * 16 + wid * 4 + g;
    if (n >= Nn) return;
    int b = offs[n], e = offs[n + 1];
    float2 aldn = *(const float2*)(ald + (size_t)n * 2);
    float bd0 = dec_ord(gmax[0]) + aldn.x; bd0 = (bd0 > 0.f) ? bd0 : NEG_SLOPE * bd0;
    float bd1 = dec_ord(gmax[1]) + aldn.y; bd1 = (bd1 > 0.f) ? bd1 : NEG_SLOPE * bd1;

    float acc[8];
    #pragma unroll
    for (int j = 0; j < 8; ++j) acc[j] = 0.f;
    float den0 = 0.f, den1 = 0.f;

    for (int base = b; base < e; base += 16) {
        int cnt = min(16, e - base);
        int   s1 = 0;
        float e0r = 0.f, e1r = 0.f;
        if (l < cnt) {
            s1 = csr[base + l];
            float2 as = *(const float2*)(als + (size_t)s1 * 2);
            float l0 = as.x + aldn.x; l0 = (l0 > 0.f) ? l0 : NEG_SLOPE * l0;
            float l1 = as.y + aldn.y; l1 = (l1 > 0.f) ? l1 : NEG_SLOPE * l1;
            e0r = __expf(l0 - bd0);
            e1r = __expf(l1 - bd1);
            den0 += e0r; den1 += e1r;
        }
        sh_s[wid][g][l]    = s1;
        sh_e[wid][g][0][l] = e0r;
        sh_e[wid][g][1][l] = e1r;
        int i = 0;
        for (; i + 1 < cnt; i += 2) {
            int   sA  = sh_s[wid][g][i];
            int   sB  = sh_s[wid][g][i + 1];
            float evA = sh_e[wid][g][head][i];
            float evB = sh_e[wid][g][head][i + 1];
            uint4 vA = *(const uint4*)(h1b + (size_t)sA * 64 + 4 * l);
            uint4 vB = *(const uint4*)(h1b + (size_t)sB * 64 + 4 * l);
            float2 f;
            f = unpack_bf16(vA.x); acc[0] += f.x * evA; acc[1] += f.y * evA;
            f = unpack_bf16(vA.y); acc[2] += f.x * evA; acc[3] += f.y * evA;
            f = unpack_bf16(vA.z); acc[4] += f.x * evA; acc[5] += f.y * evA;
            f = unpack_bf16(vA.w); acc[6] += f.x * evA; acc[7] += f.y * evA;
            f = unpack_bf16(vB.x); acc[0] += f.x * evB; acc[1] += f.y * evB;
            f = unpack_bf16(vB.y); acc[2] += f.x * evB; acc[3] += f.y * evB;
            f = unpack_bf16(vB.z); acc[4] += f.x * evB; acc[5] += f.y * evB;
            f = unpack_bf16(vB.w); acc[6] += f.x * evB; acc[7] += f.y * evB;
        }
        if (i < cnt) {
            int   s  = sh_s[wid][g][i];
            float ev = sh_e[wid][g][head][i];
            uint4 v = *(const uint4*)(h1b + (size_t)s * 64 + 4 * l);
            float2 f;
            f = unpack_bf16(v.x); acc[0] += f.x * ev; acc[1] += f.y * ev;
            f = unpack_bf16(v.y); acc[2] += f.x * ev; acc[3] += f.y * ev;
            f = unpack_bf16(v.z); acc[4] += f.x * ev; acc[5] += f.y * ev;
            f = unpack_bf16(v.w); acc[6] += f.x * ev; acc[7] += f.y * ev;
        }
    }
    #pragma unroll
    for (int m = 1; m < 16; m <<= 1) {
        den0 += __shfl_xor(den0, m);
        den1 += __shfl_xor(den1, m);
    }
    float inv = 1.f / ((head ? den1 : den0) + 1e-16f);
    int c = 8 * l;
    float4 sa = *(const float4*)(bnscale + c), sb = *(const float4*)(bnscale + c + 4);
    float4 ha = *(const float4*)(bnshift + c), hb = *(const float4*)(bnshift + c + 4);
    float o0 = fmaxf(acc[0] * inv * sa.x + ha.x, 0.f);
    float o1 = fmaxf(acc[1] * inv * sa.y + ha.y, 0.f);
    float o2 = fmaxf(acc[2] * inv * sa.z + ha.z, 0.f);
    float o3 = fmaxf(acc[3] * inv * sa.w + ha.w, 0.f);
    float o4 = fmaxf(acc[4] * inv * sb.x + hb.x, 0.f);
    float o5 = fmaxf(acc[5] * inv * sb.y + hb.y, 0.f);
    float o6 = fmaxf(acc[6] * inv * sb.z + hb.z, 0.f);
    float o7 = fmaxf(acc[7] * inv * sb.w + hb.w, 0.f);
    uint4 pk = {pack_bf16(o0, o1), pack_bf16(o2, o3), pack_bf16(o4, o5), pack_bf16(o6, o7)};
    *(uint4*)(hbnb + (size_t)n * 64 + 4 * l) = pk;
}

// ---------------- Layer 2 GEMM (A from bf16 hbnb) + fused al2; h2b rows = 20 uints ----------------
__global__ __launch_bounds__(256) void gemm2_tiled(const unsigned* __restrict__ hbnb,
                                                   const float* __restrict__ W2,
                                                   const float* __restrict__ a2s,
                                                   const float* __restrict__ a2d,
                                                   unsigned* __restrict__ h2b,
                                                   float* __restrict__ als, float* __restrict__ ald,
                                                   int Nn) {
    __shared__ float Ast[32][132];
    __shared__ float Bs[32][68];
    int t  = threadIdx.x;
    int tx = t & 15;
    int ty = t >> 4;
    int br = blockIdx.x * 128;

    float as4[4], ad4[4];
    #pragma unroll
    for (int j = 0; j < 4; ++j) {
        int c = 4 * tx + j;
        as4[j] = (c < 40) ? a2s[c] : 0.f;
        ad4[j] = (c < 40) ? a2d[c] : 0.f;
    }

    float acc[8][4];
    #pragma unroll
    for (int i = 0; i < 8; ++i)
        #pragma unroll
        for (int j = 0; j < 4; ++j) acc[i][j] = 0.f;

    int k4   = t & 7;
    int rowA = t >> 3;

    for (int k0 = 0; k0 < 128; k0 += 32) {
        #pragma unroll
        for (int i = 0; i < 4; ++i) {
            int r  = rowA + 32 * i;
            int gr = min(br + r, Nn - 1);
            uint2 v2 = *(const uint2*)(hbnb + (size_t)gr * 64 + (k0 >> 1) + 2 * k4);
            float2 f0 = unpack_bf16(v2.x), f1 = unpack_bf16(v2.y);
            Ast[4 * k4 + 0][r] = f0.x; Ast[4 * k4 + 1][r] = f0.y;
            Ast[4 * k4 + 2][r] = f1.x; Ast[4 * k4 + 3][r] = f1.y;
        }
        #pragma unroll
        for (int i = 0; i < 2; ++i) {
            int f  = t + 256 * i;
            int kk = f >> 4, c4 = f & 15;
            float4 v = {0.f, 0.f, 0.f, 0.f};
            if (c4 < 10) v = *(const float4*)(W2 + (size_t)(k0 + kk) * 40 + 4 * c4);
            *(float4*)&Bs[kk][4 * c4] = v;
        }
        __syncthreads();
        #pragma unroll 8
        for (int kk = 0; kk < 32; ++kk) {
            float4 a0 = *(const float4*)&Ast[kk][8 * ty];
            float4 a1 = *(const float4*)&Ast[kk][8 * ty + 4];
            float4 b0 = *(const float4*)&Bs[kk][4 * tx];
            float av[8] = {a0.x, a0.y, a0.z, a0.w, a1.x, a1.y, a1.z, a1.w};
            #pragma unroll
            for (int i = 0; i < 8; ++i) {
                acc[i][0] += av[i] * b0.x; acc[i][1] += av[i] * b0.y;
                acc[i][2] += av[i] * b0.z; acc[i][3] += av[i] * b0.w;
            }
        }
        __syncthreads();
    }

    #pragma unroll
    for (int i = 0; i < 8; ++i) {
        int r = br + 8 * ty + i;
        if (r < Nn && tx < 10) {
            uint2 pk = {pack_bf16(acc[i][0], acc[i][1]), pack_bf16(acc[i][2], acc[i][3])};
            *(uint2*)(h2b + (size_t)r * 20 + 2 * tx) = pk;
        }
        float ps = acc[i][0] * as4[0] + acc[i][1] * as4[1] + acc[i][2] * as4[2] + acc[i][3] * as4[3];
        float pd = acc[i][0] * ad4[0] + acc[i][1] * ad4[1] + acc[i][2] * ad4[2] + acc[i][3] * ad4[3];
        float sS = xor16_sum(ps);
        float sD = xor16_sum(pd);
        if (tx == 0 && r < Nn) { als[r] = sS; ald[r] = sD; }
    }
}

// ---------------- softagg2: 8 nodes/wave, 8 lanes/node (stride-20 h2b) ----------------
__global__ __launch_bounds__(256) void softagg2_kernel(const int* __restrict__ offs, const int* __restrict__ csr,
                            const unsigned* __restrict__ h2b,
                            const float* __restrict__ als, const float* __restrict__ ald,
                            const unsigned* __restrict__ gmax,
                            const float* __restrict__ b2,
                            float* __restrict__ out, int Nn) {
    __shared__ int   sh_s[4][8][8];
    __shared__ float sh_ev[4][8][8];
    int wid = threadIdx.x >> 6, lane = threadIdx.x & 63;
    int g = lane >> 3;
    int l = lane & 7;
    int n = blockIdx.x * 32 + wid * 8 + g;
    if (n >= Nn) return;
    int b = offs[n], e = offs[n + 1];
    float aldn = ald[n];
    float bound = dec_ord(gmax[2]) + aldn;
    bound = (bound > 0.f) ? bound : NEG_SLOPE * bound;

    float acc[8];
    #pragma unroll
    for (int j = 0; j < 8; ++j) acc[j] = 0.f;
    float den = 0.f;

    for (int base = b; base < e; base += 8) {
        int cnt = min(8, e - base);
        int   s1 = 0;
        float evr = 0.f;
        if (l < cnt) {
            s1 = csr[base + l];
            float lv = als[s1] + aldn;
            lv = (lv > 0.f) ? lv : NEG_SLOPE * lv;
            evr = __expf(lv - bound);
            den += evr;
        }
        sh_s[wid][g][l]  = s1;
        sh_ev[wid][g][l] = evr;
        if (l < 5) {
            int i = 0;
            for (; i + 1 < cnt; i += 2) {
                int   sA  = sh_s[wid][g][i];
                int   sB  = sh_s[wid][g][i + 1];
                float evA = sh_ev[wid][g][i];
                float evB = sh_ev[wid][g][i + 1];
                uint4 vA = *(const uint4*)(h2b + (size_t)sA * 20 + 4 * l);
                uint4 vB = *(const uint4*)(h2b + (size_t)sB * 20 + 4 * l);
                float2 f;
                f = unpack_bf16(vA.x); acc[0] += f.x * evA; acc[1] += f.y * evA;
                f = unpack_bf16(vA.y); acc[2] += f.x * evA; acc[3] += f.y * evA;
                f = unpack_bf16(vA.z); acc[4] += f.x * evA; acc[5] += f.y * evA;
                f = unpack_bf16(vA.w); acc[6] += f.x * evA; acc[7] += f.y * evA;
                f = unpack_bf16(vB.x); acc[0] += f.x * evB; acc[1] += f.y * evB;
                f = unpack_bf16(vB.y); acc[2] += f.x * evB; acc[3] += f.y * evB;
                f = unpack_bf16(vB.z); acc[4] += f.x * evB; acc[5] += f.y * evB;
                f = unpack_bf16(vB.w); acc[6] += f.x * evB; acc[7] += f.y * evB;
            }
            if (i < cnt) {
                int   s  = sh_s[wid][g][i];
                float ev = sh_ev[wid][g][i];
                uint4 v = *(const uint4*)(h2b + (size_t)s * 20 + 4 * l);
                float2 f;
                f = unpack_bf16(v.x); acc[0] += f.x * ev; acc[1] += f.y * ev;
                f = unpack_bf16(v.y); acc[2] += f.x * ev; acc[3] += f.y * ev;
                f = unpack_bf16(v.z); acc[4] += f.x * ev; acc[5] += f.y * ev;
                f = unpack_bf16(v.w); acc[6] += f.x * ev; acc[7] += f.y * ev;
            }
        }
    }
    #pragma unroll
    for (int m = 1; m < 8; m <<= 1) den += __shfl_xor(den, m);
    float inv = 1.f / (den + 1e-16f);
    bool valid = (l < 5);
    float vv[8];
    float lmax = -1e30f;
    if (valid) {
        int c = 8 * l;
        #pragma unroll
        for (int j = 0; j < 8; ++j) {
            vv[j] = acc[j] * inv + b2[c + j];
            lmax = fmaxf(lmax, vv[j]);
        }
    }
    float m = lmax;
    #pragma unroll
    for (int mm = 1; mm < 8; mm <<= 1) m = fmaxf(m, __shfl_xor(m, mm));
    float es = 0.f;
    if (valid) {
        #pragma unroll
        for (int j = 0; j < 8; ++j) es += __expf(vv[j] - m);
    }
    #pragma unroll
    for (int mm = 1; mm < 8; mm <<= 1) es += __shfl_xor(es, mm);
    float lse = m + logf(es);
    if (valid) {
        float4 oa = {vv[0] - lse, vv[1] - lse, vv[2] - lse, vv[3] - lse};
        float4 ob = {vv[4] - lse, vv[5] - lse, vv[6] - lse, vv[7] - lse};
        *(float4*)(out + (size_t)n * 40 + 8 * l)     = oa;
        *(float4*)(out + (size_t)n * 40 + 8 * l + 4) = ob;
    }
}

extern "C" void kernel_launch(void* const* d_in, const int* in_sizes, int n_in,
                              void* d_out, int out_size, void* d_ws, size_t ws_size,
                              hipStream_t stream) {
    const float* x    = (const float*)d_in[0];
    const int*   ei   = (const int*)d_in[1];
    const float* W1   = (const float*)d_in[2];
    const float* a1s  = (const float*)d_in[3];
    const float* a1d  = (const float*)d_in[4];
    const float* b1   = (const float*)d_in[5];
    const float* g1   = (const float*)d_in[6];
    const float* be1  = (const float*)d_in[7];
    const float* mn1  = (const float*)d_in[8];
    const float* vr1  = (const float*)d_in[9];
    const float* W2   = (const float*)d_in[10];
    const float* a2s  = (const float*)d_in[11];
    const float* a2d  = (const float*)d_in[12];
    const float* b2   = (const float*)d_in[13];
    float* out = (float*)d_out;

    const int N  = in_sizes[0] / 128;
    const int E  = in_sizes[1] / 2;
    const int Et = E + N;
    const int nCoarse = (N + COARSE_NPB - 1) >> COARSE_SHIFT;
    const int chunk   = (Et + NBLK - 1) / NBLK;

    char* p = (char*)d_ws;
    auto alloc = [&](size_t bytes) -> void* {
        void* r = (void*)p;
        p += (bytes + 255) & ~(size_t)255;
        return r;
    };
    int*      hist   = (int*)alloc((size_t)nCoarse * NBLK * 4);
    int*      cbase  = (int*)alloc((size_t)(nCoarse + 1) * 4);
    int*      offs   = (int*)alloc((size_t)(N + 1) * 4);
    unsigned* staged = (unsigned*)alloc((size_t)Et * 4);
    int*      csr    = (int*)alloc((size_t)Et * 4);
    unsigned* h1b    = (unsigned*)alloc((size_t)N * 64 * 4);
    float*    al1sv  = (float*)alloc((size_t)N * 2 * 4);
    float*    al1dv  = (float*)alloc((size_t)N * 2 * 4);
    unsigned* hbnb   = (unsigned*)alloc((size_t)N * 64 * 4);
    unsigned* h2b    = (unsigned*)alloc((size_t)N * 20 * 4);
    float*    al2sv  = (float*)alloc((size_t)N * 4);
    float*    al2dv  = (float*)alloc((size_t)N * 4);
    unsigned* gmax   = (unsigned*)alloc(4 * 4);
    float*    bnscale= (float*)alloc(128 * 4);
    float*    bnshift= (float*)alloc(128 * 4);
    (void)ws_size;

    part_hist<<<NBLK, 256, 0, stream>>>(ei, E, Et, chunk, hist, nCoarse, gmax);
    csr_mid<<<1, 1024, 0, stream>>>(hist, cbase, nCoarse);
    part_scatter<<<NBLK, 256, 0, stream>>>(ei, E, Et, chunk, hist, staged, nCoarse);
    fine_place<<<nCoarse, 512, 0, stream>>>(staged, cbase, offs, csr, N, nCoarse);

    gemm1_mfma<<<(N + 63) / 64, 256, 0, stream>>>(x, W1, a1s, a1d, h1b, al1sv, al1dv, N);
    almax_kernel<2><<<64, 256, 0, stream>>>(al1sv, gmax, 0, N, b1, g1, be1, mn1, vr1, bnscale, bnshift);
    softagg1_kernel<<<(N + 15) / 16, 256, 0, stream>>>(offs, csr, h1b, al1sv, al1dv, gmax,
                                                       bnscale, bnshift, hbnb, N);

    gemm2_tiled<<<(N + 127) / 128, 256, 0, stream>>>(hbnb, W2, a2s, a2d, h2b, al2sv, al2dv, N);
    almax_kernel<1><<<64, 256, 0, stream>>>(al2sv, gmax, 2, N, nullptr, nullptr, nullptr, nullptr,
                                            nullptr, nullptr, nullptr);
    softagg2_kernel<<<(N + 31) / 32, 256, 0, stream>>>(offs, csr, h2b, al2sv, al2dv, gmax, b2, out, N);
}